// Round 1
// baseline (3395.546 us; speedup 1.0000x reference)
//
#include <hip/hip_runtime.h>
#include <cstddef>

#define B_  64
#define T_  51
#define H_  512
#define G4_ 2048
#define V_  32000
#define R_  (T_ * B_)   // 3264

// ---------------------------------------------------------------- K0: init
// h0 = x, c0 = x, sumexp = 0  (ws is poisoned 0xAA once; atomics accumulate,
// so sumexp must be re-zeroed every call)
__global__ __launch_bounds__(256) void k0_init(const float* __restrict__ x,
                                               float* __restrict__ h0,
                                               float* __restrict__ c0,
                                               float* __restrict__ sumexp) {
    int i = blockIdx.x * 256 + threadIdx.x;
    if (i < B_ * H_) { h0[i] = x[i]; c0[i] = x[i]; }
    if (i < R_) sumexp[i] = 0.f;
}

// ---------------------------------------------------------------- K1: Xg GEMM
// Xg[r][j] = emb[tok(r)] . W_ih[j] + b_ih[j] + b_hh[j]
// r = t*64 + b ; tok = (t==0) ? START(1) : labels[b][t-1]
// grid (32 n-tiles, 51 t), block 256, tile 64x64, BK=32, micro 4x4
__global__ __launch_bounds__(256) void k1_xgates(const int* __restrict__ labels,
                                                 const float* __restrict__ emb,
                                                 const float* __restrict__ W_ih,
                                                 const float* __restrict__ b_ih,
                                                 const float* __restrict__ b_hh,
                                                 float* __restrict__ Xg) {
    __shared__ float As[64][33];
    __shared__ float Bs[64][33];
    const int t   = blockIdx.y;
    const int n0  = blockIdx.x * 64;
    const int tid = threadIdx.x;
    const int tm  = (tid >> 4) << 2;   // row group
    const int tn  = (tid & 15) << 2;   // col group
    const int lrow = tid >> 2;         // 0..63  (load row)
    const int lk   = (tid & 3) * 8;    // 0,8,16,24

    const int tok = (t == 0) ? 1 : labels[lrow * 50 + (t - 1)];
    const float* arow = emb + (size_t)tok * H_;
    const float* brow = W_ih + (size_t)(n0 + lrow) * H_;

    float acc[4][4] = {};
    for (int k0 = 0; k0 < H_; k0 += 32) {
        float4 a0 = *(const float4*)(arow + k0 + lk);
        float4 a1 = *(const float4*)(arow + k0 + lk + 4);
        float4 b0 = *(const float4*)(brow + k0 + lk);
        float4 b1 = *(const float4*)(brow + k0 + lk + 4);
        As[lrow][lk+0]=a0.x; As[lrow][lk+1]=a0.y; As[lrow][lk+2]=a0.z; As[lrow][lk+3]=a0.w;
        As[lrow][lk+4]=a1.x; As[lrow][lk+5]=a1.y; As[lrow][lk+6]=a1.z; As[lrow][lk+7]=a1.w;
        Bs[lrow][lk+0]=b0.x; Bs[lrow][lk+1]=b0.y; Bs[lrow][lk+2]=b0.z; Bs[lrow][lk+3]=b0.w;
        Bs[lrow][lk+4]=b1.x; Bs[lrow][lk+5]=b1.y; Bs[lrow][lk+6]=b1.z; Bs[lrow][lk+7]=b1.w;
        __syncthreads();
        #pragma unroll
        for (int kk = 0; kk < 32; ++kk) {
            float av[4], bv[4];
            #pragma unroll
            for (int i = 0; i < 4; ++i) av[i] = As[tm + i][kk];
            #pragma unroll
            for (int j = 0; j < 4; ++j) bv[j] = Bs[tn + j][kk];
            #pragma unroll
            for (int i = 0; i < 4; ++i)
                #pragma unroll
                for (int j = 0; j < 4; ++j) acc[i][j] += av[i] * bv[j];
        }
        __syncthreads();
    }
    #pragma unroll
    for (int i = 0; i < 4; ++i) {
        int r = t * 64 + tm + i;
        #pragma unroll
        for (int j = 0; j < 4; ++j) {
            int n = n0 + tn + j;
            Xg[(size_t)r * G4_ + n] = acc[i][j] + b_ih[n] + b_hh[n];
        }
    }
}

// ---------------------------------------------------------------- K2: LSTM step
// gates[b][j] = h_prev[b] . W_hh[j] + Xg[t*64+b][j]   (j = g*512 + u)
// block owns 4 units u0..u0+3 (x 4 gates = 16 cols) x all 64 b. grid 128.
__global__ __launch_bounds__(256) void k2_step(const float* __restrict__ Xg,
                                               const float* __restrict__ W_hh,
                                               const float* __restrict__ hprev,
                                               float* __restrict__ hnext,
                                               float* __restrict__ cbuf,
                                               float* __restrict__ hs, int t) {
    __shared__ float Hs[64][65];
    __shared__ float Ws[16][65];
    __shared__ float Gt[64][17];
    const int tid = threadIdx.x;
    const int u0  = blockIdx.x * 4;
    const int tn  = tid & 15;    // col 0..15  (g = tn>>2, uu = tn&3)
    const int tmg = tid >> 4;    // row group 0..15

    // load indices
    const int lb = tid >> 2;           // 0..63
    const int lk = (tid & 3) * 16;     // 0..48
    const int wn = tid >> 4;           // 0..15 (Ws row)
    const int wk = (tid & 15) * 4;     // 0..60
    const int jw = ((wn >> 2) * 512) + u0 + (wn & 3);
    const float* wrow = W_hh + (size_t)jw * H_;

    float acc[4] = {0.f, 0.f, 0.f, 0.f};
    for (int k0 = 0; k0 < H_; k0 += 64) {
        #pragma unroll
        for (int q = 0; q < 16; ++q) Hs[lb][lk + q] = hprev[lb * H_ + k0 + lk + q];
        #pragma unroll
        for (int q = 0; q < 4; ++q) Ws[wn][wk + q] = wrow[k0 + wk + q];
        __syncthreads();
        #pragma unroll
        for (int kk = 0; kk < 64; ++kk) {
            float w = Ws[tn][kk];
            acc[0] += Hs[tmg * 4 + 0][kk] * w;
            acc[1] += Hs[tmg * 4 + 1][kk] * w;
            acc[2] += Hs[tmg * 4 + 2][kk] * w;
            acc[3] += Hs[tmg * 4 + 3][kk] * w;
        }
        __syncthreads();
    }
    // stash gate tile (+Xg) for the 4-gate exchange
    const int g  = tn >> 2, uu = tn & 3;
    const int j  = g * 512 + u0 + uu;
    #pragma unroll
    for (int i = 0; i < 4; ++i) {
        int b = tmg * 4 + i;
        Gt[b][tn] = acc[i] + Xg[(size_t)(t * 64 + b) * G4_ + j];
    }
    __syncthreads();
    // LSTM update: thread -> (b, uu2)
    const int b2  = tid >> 2;
    const int uu2 = tid & 3;
    const int u   = u0 + uu2;
    float gi = Gt[b2][uu2];
    float gf = Gt[b2][4 + uu2];
    float gg = Gt[b2][8 + uu2];
    float go = Gt[b2][12 + uu2];
    float si = 1.f / (1.f + __expf(-gi));
    float sf = 1.f / (1.f + __expf(-gf));
    float tg = tanhf(gg);
    float so = 1.f / (1.f + __expf(-go));
    float c  = sf * cbuf[b2 * H_ + u] + si * tg;
    float h  = so * tanhf(c);
    cbuf[b2 * H_ + u]  = c;
    hnext[b2 * H_ + u] = h;
    hs[(size_t)(t * 64 + b2) * H_ + u] = h;
}

// ---------------------------------------------------------------- K3: FC + lse
// logits tile 64 rows x 128 vocab; partial sumexp per row via shuffle+atomic;
// target logit written by its unique owner. No max-subtraction (|logit| small,
// exp safe in fp32).
// grid (250, 51), block 256, BK=32, micro 4x8 (cols interleaved by 16).
__global__ __launch_bounds__(256) void k3_fc(const float* __restrict__ hs,
                                             const float* __restrict__ fc_W,
                                             const float* __restrict__ fc_b,
                                             const int* __restrict__ labels,
                                             float* __restrict__ sumexp,
                                             float* __restrict__ tgtlog) {
    __shared__ float As[64][33];
    __shared__ float Bs[128][33];
    const int t   = blockIdx.y;
    const int v0  = blockIdx.x * 128;
    const int tid = threadIdx.x;
    const int tm  = (tid >> 4) << 2;   // rows tm..tm+3
    const int tn  = tid & 15;          // cols tn + 16*j
    const int lrow  = tid >> 2;        // A load: 0..63
    const int lk    = (tid & 3) * 8;
    const int lrowB = tid >> 1;        // B load: 0..127
    const int lkB   = (tid & 1) * 16;

    const float* arow = hs + (size_t)(t * 64 + lrow) * H_;
    const float* brow = fc_W + (size_t)(v0 + lrowB) * H_;

    float acc[4][8] = {};
    for (int k0 = 0; k0 < H_; k0 += 32) {
        float4 a0 = *(const float4*)(arow + k0 + lk);
        float4 a1 = *(const float4*)(arow + k0 + lk + 4);
        As[lrow][lk+0]=a0.x; As[lrow][lk+1]=a0.y; As[lrow][lk+2]=a0.z; As[lrow][lk+3]=a0.w;
        As[lrow][lk+4]=a1.x; As[lrow][lk+5]=a1.y; As[lrow][lk+6]=a1.z; As[lrow][lk+7]=a1.w;
        #pragma unroll
        for (int q = 0; q < 4; ++q) {
            float4 b4 = *(const float4*)(brow + k0 + lkB + q * 4);
            Bs[lrowB][lkB+q*4+0]=b4.x; Bs[lrowB][lkB+q*4+1]=b4.y;
            Bs[lrowB][lkB+q*4+2]=b4.z; Bs[lrowB][lkB+q*4+3]=b4.w;
        }
        __syncthreads();
        #pragma unroll
        for (int kk = 0; kk < 32; ++kk) {
            float av[4], bv[8];
            #pragma unroll
            for (int i = 0; i < 4; ++i) av[i] = As[tm + i][kk];
            #pragma unroll
            for (int j = 0; j < 8; ++j) bv[j] = Bs[tn + j * 16][kk];
            #pragma unroll
            for (int i = 0; i < 4; ++i)
                #pragma unroll
                for (int j = 0; j < 8; ++j) acc[i][j] += av[i] * bv[j];
        }
        __syncthreads();
    }
    // epilogue: bias, exp-sum, target pick
    #pragma unroll
    for (int i = 0; i < 4; ++i) {
        const int bi  = tm + i;                 // batch row
        const int r   = t * 64 + bi;
        const int tgt = (t < 50) ? labels[bi * 50 + t] : 2;
        float lsum = 0.f;
        #pragma unroll
        for (int j = 0; j < 8; ++j) {
            int v = v0 + tn + j * 16;
            float lg = acc[i][j] + fc_b[v];
            lsum += __expf(lg);
            if (v == tgt) tgtlog[r] = lg;
        }
        // reduce across the 16 lanes sharing this row group
        lsum += __shfl_xor(lsum, 1, 16);
        lsum += __shfl_xor(lsum, 2, 16);
        lsum += __shfl_xor(lsum, 4, 16);
        lsum += __shfl_xor(lsum, 8, 16);
        if (tn == 0) atomicAdd(&sumexp[r], lsum);
    }
}

// ---------------------------------------------------------------- K4: loss
__global__ __launch_bounds__(256) void k4_loss(const float* __restrict__ sumexp,
                                               const float* __restrict__ tgtlog,
                                               float* __restrict__ out) {
    __shared__ float red[256];
    float s = 0.f;
    for (int r = threadIdx.x; r < R_; r += 256) s += logf(sumexp[r]) - tgtlog[r];
    red[threadIdx.x] = s;
    __syncthreads();
    for (int st = 128; st > 0; st >>= 1) {
        if (threadIdx.x < st) red[threadIdx.x] += red[threadIdx.x + st];
        __syncthreads();
    }
    if (threadIdx.x == 0) out[0] = red[0] / 64.0f;
}

// ----------------------------------------------------------------
extern "C" void kernel_launch(void* const* d_in, const int* in_sizes, int n_in,
                              void* d_out, int out_size, void* d_ws, size_t ws_size,
                              hipStream_t stream) {
    const float* x      = (const float*)d_in[0];
    const int*   labels = (const int*)d_in[1];
    const float* emb    = (const float*)d_in[2];
    const float* W_ih   = (const float*)d_in[3];
    const float* W_hh   = (const float*)d_in[4];
    const float* b_ih   = (const float*)d_in[5];
    const float* b_hh   = (const float*)d_in[6];
    const float* fc_W   = (const float*)d_in[7];
    const float* fc_b   = (const float*)d_in[8];
    float* out = (float*)d_out;

    // workspace layout (floats): total ~8.46M floats = ~33.9 MB
    float* ws     = (float*)d_ws;
    float* Xg     = ws;                          // R_*G4_
    float* hs     = Xg + (size_t)R_ * G4_;       // R_*H_
    float* hping  = hs + (size_t)R_ * H_;        // 2*B_*H_
    float* cbuf   = hping + 2 * B_ * H_;         // B_*H_
    float* sumexp = cbuf + B_ * H_;              // R_
    float* tgtl   = sumexp + R_;                 // R_

    k0_init<<<128, 256, 0, stream>>>(x, hping, cbuf, sumexp);
    k1_xgates<<<dim3(32, 51), 256, 0, stream>>>(labels, emb, W_ih, b_ih, b_hh, Xg);
    for (int t = 0; t < T_; ++t) {
        const float* hp = hping + (size_t)(t & 1) * B_ * H_;
        float*       hn = hping + (size_t)((t & 1) ^ 1) * B_ * H_;
        k2_step<<<128, 256, 0, stream>>>(Xg, W_hh, hp, hn, cbuf, hs, t);
    }
    k3_fc<<<dim3(250, 51), 256, 0, stream>>>(hs, fc_W, fc_b, labels, sumexp, tgtl);
    k4_loss<<<1, 256, 0, stream>>>(sumexp, tgtl, out);
}

// Round 2
// 853.325 us; speedup vs baseline: 3.9792x; 3.9792x over previous
//
#include <hip/hip_runtime.h>
#include <cstddef>
#include <cstdint>

#define B_  64
#define T_  51
#define H_  512
#define G4_ 2048
#define V_  32000
#define R_  (T_ * B_)   // 3264

typedef __attribute__((ext_vector_type(8))) short bf16x8;
typedef __attribute__((ext_vector_type(4))) float f32x4;

__device__ __forceinline__ uint16_t f2bf(float f) {   // RNE float->bf16
    uint32_t u = __float_as_uint(f);
    u += 0x7FFFu + ((u >> 16) & 1u);
    return (uint16_t)(u >> 16);
}

// ---------------------------------------------------------------- K0: init
// hx = bf16(x); sumexp = 0; bar = 0   (all per-call: ws not re-poisoned)
__global__ __launch_bounds__(256) void k0_init(const float* __restrict__ x,
                                               uint16_t* __restrict__ hx,
                                               float* __restrict__ sumexp,
                                               int* __restrict__ bar) {
    int i = blockIdx.x * 256 + threadIdx.x;
    if (i < B_ * H_) hx[i] = f2bf(x[i]);
    if (i < R_) sumexp[i] = 0.f;
    if (i == 0) *bar = 0;
}

// ---------------------------------------------------------------- Kcvt: fc_W -> bf16
__global__ __launch_bounds__(256) void kcvt(const float* __restrict__ src,
                                            uint16_t* __restrict__ dst, int n8) {
    int i = blockIdx.x * 256 + threadIdx.x;
    if (i >= n8) return;
    const float4* s = (const float4*)src + (size_t)i * 2;
    float4 f0 = s[0], f1 = s[1];
    union { uint16_t h[8]; uint4 u; } p;
    p.h[0]=f2bf(f0.x); p.h[1]=f2bf(f0.y); p.h[2]=f2bf(f0.z); p.h[3]=f2bf(f0.w);
    p.h[4]=f2bf(f1.x); p.h[5]=f2bf(f1.y); p.h[6]=f2bf(f1.z); p.h[7]=f2bf(f1.w);
    ((uint4*)dst)[i] = p.u;
}

// ---------------------------------------------------------------- K1: Xg GEMM (fp32, unchanged)
__global__ __launch_bounds__(256) void k1_xgates(const int* __restrict__ labels,
                                                 const float* __restrict__ emb,
                                                 const float* __restrict__ W_ih,
                                                 const float* __restrict__ b_ih,
                                                 const float* __restrict__ b_hh,
                                                 float* __restrict__ Xg) {
    __shared__ float As[64][33];
    __shared__ float Bs[64][33];
    const int t   = blockIdx.y;
    const int n0  = blockIdx.x * 64;
    const int tid = threadIdx.x;
    const int tm  = (tid >> 4) << 2;
    const int tn  = (tid & 15) << 2;
    const int lrow = tid >> 2;
    const int lk   = (tid & 3) * 8;

    const int tok = (t == 0) ? 1 : labels[lrow * 50 + (t - 1)];
    const float* arow = emb + (size_t)tok * H_;
    const float* brow = W_ih + (size_t)(n0 + lrow) * H_;

    float acc[4][4] = {};
    for (int k0 = 0; k0 < H_; k0 += 32) {
        float4 a0 = *(const float4*)(arow + k0 + lk);
        float4 a1 = *(const float4*)(arow + k0 + lk + 4);
        float4 b0 = *(const float4*)(brow + k0 + lk);
        float4 b1 = *(const float4*)(brow + k0 + lk + 4);
        As[lrow][lk+0]=a0.x; As[lrow][lk+1]=a0.y; As[lrow][lk+2]=a0.z; As[lrow][lk+3]=a0.w;
        As[lrow][lk+4]=a1.x; As[lrow][lk+5]=a1.y; As[lrow][lk+6]=a1.z; As[lrow][lk+7]=a1.w;
        Bs[lrow][lk+0]=b0.x; Bs[lrow][lk+1]=b0.y; Bs[lrow][lk+2]=b0.z; Bs[lrow][lk+3]=b0.w;
        Bs[lrow][lk+4]=b1.x; Bs[lrow][lk+5]=b1.y; Bs[lrow][lk+6]=b1.z; Bs[lrow][lk+7]=b1.w;
        __syncthreads();
        #pragma unroll
        for (int kk = 0; kk < 32; ++kk) {
            float av[4], bv[4];
            #pragma unroll
            for (int i = 0; i < 4; ++i) av[i] = As[tm + i][kk];
            #pragma unroll
            for (int j = 0; j < 4; ++j) bv[j] = Bs[tn + j][kk];
            #pragma unroll
            for (int i = 0; i < 4; ++i)
                #pragma unroll
                for (int j = 0; j < 4; ++j) acc[i][j] += av[i] * bv[j];
        }
        __syncthreads();
    }
    #pragma unroll
    for (int i = 0; i < 4; ++i) {
        int r = t * 64 + tm + i;
        #pragma unroll
        for (int j = 0; j < 4; ++j) {
            int n = n0 + tn + j;
            Xg[(size_t)r * G4_ + n] = acc[i][j] + b_ih[n] + b_hh[n];
        }
    }
}

// ---------------------------------------------------------------- K2p: persistent LSTM
// 32 blocks (1/CU, co-resident). Block owns 16 units u0..u0+15 (=64 gate cols).
// W_hh slice bf16 resident in LDS all 51 steps. h exchanged via global bf16 +
// device-scope barrier (G16: fences for cross-XCD L2 coherence).
// Wave w = m-frag (rows w*16..+15); nf = gate g. D-layout gives each lane all
// 4 gates for (b = w*16+lhi*4+q, u = u0+l15) -> LSTM update fully in-register.
__global__ __launch_bounds__(256) void k2p(const uint16_t* __restrict__ hx,
                                           const float* __restrict__ x,
                                           const float* __restrict__ Xg,
                                           const float* __restrict__ W_hh,
                                           uint16_t* __restrict__ hs,
                                           int* __restrict__ bar) {
    extern __shared__ uint16_t lds2[];
    uint16_t* Wl = lds2;             // [64][520] bf16 (padded: 2-way max)
    uint16_t* Hl = lds2 + 64 * 520;  // [64][520]
    const int tid  = threadIdx.x;
    const int u0   = blockIdx.x * 16;
    const int w    = tid >> 6;
    const int lane = tid & 63;
    const int l15  = lane & 15;
    const int lhi  = lane >> 4;

    // load W_hh slice -> bf16 LDS. LDS row c = g*16+uu  <->  W row g*512+u0+uu
    {
        const int c = tid >> 2;
        const int q = tid & 3;
        const int j = (c >> 4) * 512 + u0 + (c & 15);
        const float* src = W_hh + (size_t)j * H_ + q * 128;
        uint16_t* dst = Wl + c * 520 + q * 128;
        #pragma unroll
        for (int i = 0; i < 128; i += 8) {
            float4 f0 = *(const float4*)(src + i);
            float4 f1 = *(const float4*)(src + i + 4);
            union { uint16_t h[8]; uint4 u; } p;
            p.h[0]=f2bf(f0.x); p.h[1]=f2bf(f0.y); p.h[2]=f2bf(f0.z); p.h[3]=f2bf(f0.w);
            p.h[4]=f2bf(f1.x); p.h[5]=f2bf(f1.y); p.h[6]=f2bf(f1.z); p.h[7]=f2bf(f1.w);
            *(uint4*)(dst + i) = p.u;
        }
    }
    // c-state (fp32, registers): this lane's 4 (b,u) states
    float cst[4];
    #pragma unroll
    for (int q = 0; q < 4; ++q)
        cst[q] = x[(size_t)(w * 16 + lhi * 4 + q) * H_ + u0 + l15];
    __syncthreads();

    for (int t = 0; t < T_; ++t) {
        const uint16_t* hp = (t == 0) ? hx : hs + (size_t)(t - 1) * B_ * H_;
        // stage full h_prev (64x512 bf16) into LDS, coalesced
        #pragma unroll
        for (int r = 0; r < 16; ++r) {
            int idx = r * 256 + tid;
            int row = idx >> 6, seg = idx & 63;
            *(uint4*)(Hl + row * 520 + seg * 8) = *(const uint4*)(hp + row * H_ + seg * 8);
        }
        __syncthreads();
        f32x4 acc[4];
        #pragma unroll
        for (int nf = 0; nf < 4; ++nf) acc[nf] = (f32x4){0.f, 0.f, 0.f, 0.f};
        #pragma unroll
        for (int ks = 0; ks < 16; ++ks) {
            bf16x8 a = *(const bf16x8*)(Hl + (w * 16 + l15) * 520 + ks * 32 + lhi * 8);
            #pragma unroll
            for (int nf = 0; nf < 4; ++nf) {
                bf16x8 b = *(const bf16x8*)(Wl + (nf * 16 + l15) * 520 + ks * 32 + lhi * 8);
                acc[nf] = __builtin_amdgcn_mfma_f32_16x16x32_bf16(a, b, acc[nf], 0, 0, 0);
            }
        }
        #pragma unroll
        for (int q = 0; q < 4; ++q) {
            const int b = w * 16 + lhi * 4 + q;
            const size_t xr = (size_t)(t * 64 + b) * G4_ + u0 + l15;
            float gi = acc[0][q] + Xg[xr];
            float gf = acc[1][q] + Xg[xr + 512];
            float gg = acc[2][q] + Xg[xr + 1024];
            float go = acc[3][q] + Xg[xr + 1536];
            float si = 1.f / (1.f + __expf(-gi));
            float sf = 1.f / (1.f + __expf(-gf));
            float tg = tanhf(gg);
            float so = 1.f / (1.f + __expf(-go));
            float cc = sf * cst[q] + si * tg;
            cst[q] = cc;
            hs[(size_t)(t * 64 + b) * H_ + u0 + l15] = f2bf(so * tanhf(cc));
        }
        __syncthreads();          // drains all waves' vmem (compiler: vmcnt(0) before s_barrier)
        if (tid == 0) {
            __threadfence();      // release: writeback XCD L2 (covers whole block's stores)
            __hip_atomic_fetch_add(bar, 1, __ATOMIC_RELEASE, __HIP_MEMORY_SCOPE_AGENT);
            int target = 32 * (t + 1);
            while (__hip_atomic_load(bar, __ATOMIC_ACQUIRE, __HIP_MEMORY_SCOPE_AGENT) < target) {
                __builtin_amdgcn_s_sleep(2);
            }
        }
        __syncthreads();
        __threadfence();          // acquire: invalidate L1/L2 before reading others' h
    }
}

// ---------------------------------------------------------------- K3: FC + lse (MFMA bf16)
// tile 64 rows x 256 vocab, BK=64, 4 waves (wave w -> vocab cols w*64..+63).
// CVT=1: fc_W is fp32, convert during staging; CVT=0: pre-converted bf16.
template<int CVT>
__global__ __launch_bounds__(256) void k3_mfma(const uint16_t* __restrict__ hsb,
                                               const void* __restrict__ fcw,
                                               const float* __restrict__ fc_b,
                                               const int* __restrict__ labels,
                                               float* __restrict__ sumexp,
                                               float* __restrict__ tgtlog) {
    __shared__ uint16_t Al[64 * 72];    // stride 72 bf16 (144B): 2-way max
    __shared__ uint16_t Bl[256 * 72];
    const int t    = blockIdx.x;
    const int v0   = blockIdx.y * 256;
    const int tid  = threadIdx.x;
    const int w    = tid >> 6;
    const int lane = tid & 63;
    const int l15  = lane & 15;
    const int lhi  = lane >> 4;

    f32x4 acc[4][4];
    #pragma unroll
    for (int mi = 0; mi < 4; ++mi)
        #pragma unroll
        for (int nf = 0; nf < 4; ++nf) acc[mi][nf] = (f32x4){0.f, 0.f, 0.f, 0.f};

    for (int k0 = 0; k0 < H_; k0 += 64) {
        #pragma unroll
        for (int r = 0; r < 2; ++r) {   // A: 64 rows x 64 bf16
            int idx = r * 256 + tid, row = idx >> 3, seg = idx & 7;
            *(uint4*)(Al + row * 72 + seg * 8) =
                *(const uint4*)(hsb + (size_t)(t * 64 + row) * H_ + k0 + seg * 8);
        }
        #pragma unroll
        for (int r = 0; r < 8; ++r) {   // B: 256 rows x 64 bf16
            int idx = r * 256 + tid, row = idx >> 3, seg = idx & 7;
            if (CVT) {
                const float* s = (const float*)fcw + (size_t)(v0 + row) * H_ + k0 + seg * 8;
                float4 f0 = *(const float4*)s;
                float4 f1 = *(const float4*)(s + 4);
                union { uint16_t h[8]; uint4 u; } p;
                p.h[0]=f2bf(f0.x); p.h[1]=f2bf(f0.y); p.h[2]=f2bf(f0.z); p.h[3]=f2bf(f0.w);
                p.h[4]=f2bf(f1.x); p.h[5]=f2bf(f1.y); p.h[6]=f2bf(f1.z); p.h[7]=f2bf(f1.w);
                *(uint4*)(Bl + row * 72 + seg * 8) = p.u;
            } else {
                *(uint4*)(Bl + row * 72 + seg * 8) =
                    *(const uint4*)((const uint16_t*)fcw + (size_t)(v0 + row) * H_ + k0 + seg * 8);
            }
        }
        __syncthreads();
        #pragma unroll
        for (int ks = 0; ks < 2; ++ks) {
            bf16x8 a[4];
            #pragma unroll
            for (int mi = 0; mi < 4; ++mi)
                a[mi] = *(const bf16x8*)(Al + (mi * 16 + l15) * 72 + ks * 32 + lhi * 8);
            #pragma unroll
            for (int nf = 0; nf < 4; ++nf) {
                bf16x8 b = *(const bf16x8*)(Bl + (w * 64 + nf * 16 + l15) * 72 + ks * 32 + lhi * 8);
                #pragma unroll
                for (int mi = 0; mi < 4; ++mi)
                    acc[mi][nf] = __builtin_amdgcn_mfma_f32_16x16x32_bf16(a[mi], b, acc[mi][nf], 0, 0, 0);
            }
        }
        __syncthreads();
    }
    // epilogue: bias + exp-sum (16-lane shuffle reduce) + target-logit pick
    float bias[4];
    #pragma unroll
    for (int nf = 0; nf < 4; ++nf) bias[nf] = fc_b[v0 + w * 64 + nf * 16 + l15];
    #pragma unroll
    for (int mi = 0; mi < 4; ++mi) {
        #pragma unroll
        for (int q = 0; q < 4; ++q) {
            const int b = mi * 16 + lhi * 4 + q;
            const int r = t * 64 + b;
            const int tgt = (t < 50) ? labels[b * 50 + t] : 2;
            float lsum = 0.f;
            #pragma unroll
            for (int nf = 0; nf < 4; ++nf) {
                const int v = v0 + w * 64 + nf * 16 + l15;
                float lg = acc[mi][nf][q] + bias[nf];
                lsum += __expf(lg);
                if (v == tgt) tgtlog[r] = lg;
            }
            lsum += __shfl_xor(lsum, 1, 16);
            lsum += __shfl_xor(lsum, 2, 16);
            lsum += __shfl_xor(lsum, 4, 16);
            lsum += __shfl_xor(lsum, 8, 16);
            if (l15 == 0) atomicAdd(&sumexp[r], lsum);
        }
    }
}

// ---------------------------------------------------------------- K4: loss
__global__ __launch_bounds__(256) void k4_loss(const float* __restrict__ sumexp,
                                               const float* __restrict__ tgtlog,
                                               float* __restrict__ out) {
    __shared__ float red[256];
    float s = 0.f;
    for (int r = threadIdx.x; r < R_; r += 256) s += logf(sumexp[r]) - tgtlog[r];
    red[threadIdx.x] = s;
    __syncthreads();
    for (int st = 128; st > 0; st >>= 1) {
        if (threadIdx.x < st) red[threadIdx.x] += red[threadIdx.x + st];
        __syncthreads();
    }
    if (threadIdx.x == 0) out[0] = red[0] / 64.0f;
}

// ----------------------------------------------------------------
extern "C" void kernel_launch(void* const* d_in, const int* in_sizes, int n_in,
                              void* d_out, int out_size, void* d_ws, size_t ws_size,
                              hipStream_t stream) {
    const float* x      = (const float*)d_in[0];
    const int*   labels = (const int*)d_in[1];
    const float* emb    = (const float*)d_in[2];
    const float* W_ih   = (const float*)d_in[3];
    const float* W_hh   = (const float*)d_in[4];
    const float* b_ih   = (const float*)d_in[5];
    const float* b_hh   = (const float*)d_in[6];
    const float* fc_W   = (const float*)d_in[7];
    const float* fc_b   = (const float*)d_in[8];
    float* out = (float*)d_out;

    char* p = (char*)d_ws;
    float*    Xg     = (float*)p;     p += (size_t)R_ * G4_ * 4;   // 26.7 MB
    uint16_t* hsb    = (uint16_t*)p;  p += (size_t)R_ * H_ * 2;    // 3.3 MB
    uint16_t* hx     = (uint16_t*)p;  p += (size_t)B_ * H_ * 2;
    float*    sumexp = (float*)p;     p += (size_t)R_ * 4;
    float*    tgtl   = (float*)p;     p += (size_t)R_ * 4;
    int*      bar    = (int*)p;       p += 64;
    uint16_t* fcwb   = (uint16_t*)p;  p += (size_t)V_ * H_ * 2;    // 32.8 MB (optional)
    const bool pre = ((size_t)(p - (char*)d_ws) <= ws_size);

    k0_init<<<128, 256, 0, stream>>>(x, hx, sumexp, bar);
    if (pre) kcvt<<<8000, 256, 0, stream>>>(fc_W, fcwb, (V_ * H_) / 8);
    k1_xgates<<<dim3(32, 51), 256, 0, stream>>>(labels, emb, W_ih, b_ih, b_hh, Xg);
    k2p<<<32, 256, 2 * 64 * 520 * 2, stream>>>(hx, x, Xg, W_hh, hsb, bar);
    if (pre) k3_mfma<0><<<dim3(51, 125), 256, 0, stream>>>(hsb, fcwb, fc_b, labels, sumexp, tgtl);
    else     k3_mfma<1><<<dim3(51, 125), 256, 0, stream>>>(hsb, fc_W, fc_b, labels, sumexp, tgtl);
    k4_loss<<<1, 256, 0, stream>>>(sumexp, tgtl, out);
}

// Round 3
// 646.662 us; speedup vs baseline: 5.2509x; 1.3196x over previous
//
#include <hip/hip_runtime.h>
#include <cstddef>
#include <cstdint>

#define B_  64
#define T_  51
#define H_  512
#define G4_ 2048
#define V_  32000
#define R_  (T_ * B_)   // 3264

typedef __attribute__((ext_vector_type(8))) short bf16x8;
typedef __attribute__((ext_vector_type(4))) float f32x4;
typedef unsigned long long ull;

__device__ __forceinline__ uint16_t f2bf(float f) {   // RNE float->bf16
    uint32_t u = __float_as_uint(f);
    u += 0x7FFFu + ((u >> 16) & 1u);
    return (uint16_t)(u >> 16);
}

// ---------------------------------------------------------------- K0: init
__global__ __launch_bounds__(256) void k0_init(const float* __restrict__ x,
                                               uint16_t* __restrict__ hx,
                                               float* __restrict__ sumexp,
                                               int* __restrict__ bar) {
    int i = blockIdx.x * 256 + threadIdx.x;
    if (i < B_ * H_) hx[i] = f2bf(x[i]);
    if (i < R_) sumexp[i] = 0.f;
    if (i == 0) *bar = 0;
}

// ---------------------------------------------------------------- Kcvt: f32 -> bf16
__global__ __launch_bounds__(256) void kcvt(const float* __restrict__ src,
                                            uint16_t* __restrict__ dst, int n8) {
    int i = blockIdx.x * 256 + threadIdx.x;
    if (i >= n8) return;
    const float4* s = (const float4*)src + (size_t)i * 2;
    float4 f0 = s[0], f1 = s[1];
    union { uint16_t h[8]; uint4 u; } p;
    p.h[0]=f2bf(f0.x); p.h[1]=f2bf(f0.y); p.h[2]=f2bf(f0.z); p.h[3]=f2bf(f0.w);
    p.h[4]=f2bf(f1.x); p.h[5]=f2bf(f1.y); p.h[6]=f2bf(f1.z); p.h[7]=f2bf(f1.w);
    ((uint4*)dst)[i] = p.u;
}

// ---------------------------------------------------------------- K1: Xg GEMM (bf16 MFMA)
// Xg[r][j] = emb[tok(r)] . W_ih[j] + b_ih[j] + b_hh[j]; tile 64x256, BK=64.
// grid (8 n-tiles, 51 t). CVT=1: W_ih fp32 converted in staging.
template<int CVT>
__global__ __launch_bounds__(256, 2) void k1_mfma(const int* __restrict__ labels,
                                                  const float* __restrict__ emb,
                                                  const void* __restrict__ wih,
                                                  const float* __restrict__ b_ih,
                                                  const float* __restrict__ b_hh,
                                                  float* __restrict__ Xg) {
    __shared__ uint16_t Al[64 * 72];
    __shared__ uint16_t Bl[256 * 72];
    const int t    = blockIdx.y;
    const int n0   = blockIdx.x * 256;
    const int tid  = threadIdx.x;
    const int w    = tid >> 6;
    const int lane = tid & 63;
    const int l15  = lane & 15;
    const int lhi  = lane >> 4;

    f32x4 acc[4][4];
    #pragma unroll
    for (int mi = 0; mi < 4; ++mi)
        #pragma unroll
        for (int nf = 0; nf < 4; ++nf) acc[mi][nf] = (f32x4){0.f, 0.f, 0.f, 0.f};

    for (int k0 = 0; k0 < H_; k0 += 64) {
        #pragma unroll
        for (int r = 0; r < 2; ++r) {       // A: 64 rows x 64, gather+convert
            int idx = r * 256 + tid, row = idx >> 3, seg = idx & 7;
            int tok = (t == 0) ? 1 : labels[row * 50 + (t - 1)];
            const float* s = emb + (size_t)tok * H_ + k0 + seg * 8;
            float4 f0 = *(const float4*)s;
            float4 f1 = *(const float4*)(s + 4);
            union { uint16_t h[8]; uint4 u; } p;
            p.h[0]=f2bf(f0.x); p.h[1]=f2bf(f0.y); p.h[2]=f2bf(f0.z); p.h[3]=f2bf(f0.w);
            p.h[4]=f2bf(f1.x); p.h[5]=f2bf(f1.y); p.h[6]=f2bf(f1.z); p.h[7]=f2bf(f1.w);
            *(uint4*)(Al + row * 72 + seg * 8) = p.u;
        }
        #pragma unroll
        for (int r = 0; r < 8; ++r) {       // B: 256 rows x 64
            int idx = r * 256 + tid, row = idx >> 3, seg = idx & 7;
            if (CVT) {
                const float* s = (const float*)wih + (size_t)(n0 + row) * H_ + k0 + seg * 8;
                float4 f0 = *(const float4*)s;
                float4 f1 = *(const float4*)(s + 4);
                union { uint16_t h[8]; uint4 u; } p;
                p.h[0]=f2bf(f0.x); p.h[1]=f2bf(f0.y); p.h[2]=f2bf(f0.z); p.h[3]=f2bf(f0.w);
                p.h[4]=f2bf(f1.x); p.h[5]=f2bf(f1.y); p.h[6]=f2bf(f1.z); p.h[7]=f2bf(f1.w);
                *(uint4*)(Bl + row * 72 + seg * 8) = p.u;
            } else {
                *(uint4*)(Bl + row * 72 + seg * 8) =
                    *(const uint4*)((const uint16_t*)wih + (size_t)(n0 + row) * H_ + k0 + seg * 8);
            }
        }
        __syncthreads();
        #pragma unroll
        for (int ks = 0; ks < 2; ++ks) {
            bf16x8 a[4];
            #pragma unroll
            for (int mi = 0; mi < 4; ++mi)
                a[mi] = *(const bf16x8*)(Al + (mi * 16 + l15) * 72 + ks * 32 + lhi * 8);
            #pragma unroll
            for (int nf = 0; nf < 4; ++nf) {
                bf16x8 b = *(const bf16x8*)(Bl + (w * 64 + nf * 16 + l15) * 72 + ks * 32 + lhi * 8);
                #pragma unroll
                for (int mi = 0; mi < 4; ++mi)
                    acc[mi][nf] = __builtin_amdgcn_mfma_f32_16x16x32_bf16(a[mi], b, acc[mi][nf], 0, 0, 0);
            }
        }
        __syncthreads();
    }
    float bias[4];
    #pragma unroll
    for (int nf = 0; nf < 4; ++nf) {
        int col = n0 + w * 64 + nf * 16 + l15;
        bias[nf] = b_ih[col] + b_hh[col];
    }
    #pragma unroll
    for (int mi = 0; mi < 4; ++mi)
        #pragma unroll
        for (int q = 0; q < 4; ++q) {
            int b = mi * 16 + lhi * 4 + q;
            #pragma unroll
            for (int nf = 0; nf < 4; ++nf) {
                int col = n0 + w * 64 + nf * 16 + l15;
                Xg[(size_t)(t * 64 + b) * G4_ + col] = acc[mi][nf][q] + bias[nf];
            }
        }
}

// ---------------------------------------------------------------- K2p: persistent LSTM
// 32 blocks (1/CU). Block owns 16 units; W_hh slice bf16 LDS-resident.
// h exchange: agent-scope RELAXED atomics (operate at LLC -> cross-XCD coherent,
// NO threadfence / L2 writeback). A-frags load direct global->reg (each h elem
// used once per block -> LDS staging was pure overhead). Barrier: relaxed
// fetch_add + spin; ordering via __syncthreads vmcnt-drain + s_barrier.
__global__ __launch_bounds__(256) void k2p(const uint16_t* __restrict__ hx,
                                           const float* __restrict__ x,
                                           const float* __restrict__ Xg,
                                           const float* __restrict__ W_hh,
                                           uint16_t* __restrict__ hs,
                                           int* __restrict__ bar) {
    extern __shared__ uint16_t Wl[];     // [64][520] bf16
    const int tid  = threadIdx.x;
    const int u0   = blockIdx.x * 16;
    const int w    = tid >> 6;
    const int lane = tid & 63;
    const int l15  = lane & 15;
    const int lhi  = lane >> 4;

    {   // W_hh slice -> bf16 LDS. LDS row c = g*16+uu  <->  W row g*512+u0+uu
        const int c = tid >> 2;
        const int q = tid & 3;
        const int j = (c >> 4) * 512 + u0 + (c & 15);
        const float* src = W_hh + (size_t)j * H_ + q * 128;
        uint16_t* dst = Wl + c * 520 + q * 128;
        #pragma unroll
        for (int i = 0; i < 128; i += 8) {
            float4 f0 = *(const float4*)(src + i);
            float4 f1 = *(const float4*)(src + i + 4);
            union { uint16_t h[8]; uint4 u; } p;
            p.h[0]=f2bf(f0.x); p.h[1]=f2bf(f0.y); p.h[2]=f2bf(f0.z); p.h[3]=f2bf(f0.w);
            p.h[4]=f2bf(f1.x); p.h[5]=f2bf(f1.y); p.h[6]=f2bf(f1.z); p.h[7]=f2bf(f1.w);
            *(uint4*)(dst + i) = p.u;
        }
    }
    float cst[4];
    #pragma unroll
    for (int q = 0; q < 4; ++q)
        cst[q] = x[(size_t)(w * 16 + lhi * 4 + q) * H_ + u0 + l15];
    __syncthreads();

    for (int t = 0; t < T_; ++t) {
        // prefetch Xg (race-free, cached) to hide under A-load latency
        float xg[4][4];
        #pragma unroll
        for (int g = 0; g < 4; ++g)
            #pragma unroll
            for (int q = 0; q < 4; ++q)
                xg[g][q] = Xg[(size_t)(t * 64 + w * 16 + lhi * 4 + q) * G4_ + g * 512 + u0 + l15];

        // A-frags: 16 ks x 16B direct from LLC (agent relaxed atomics)
        const uint16_t* hp = (t == 0) ? hx : hs + (size_t)(t - 1) * B_ * H_;
        const int arow = w * 16 + l15;
        ull ha[16][2];
        #pragma unroll
        for (int ks = 0; ks < 16; ++ks) {
            ull* p = (ull*)(hp + (size_t)arow * H_ + ks * 32 + lhi * 8);
            ha[ks][0] = __hip_atomic_load(p,     __ATOMIC_RELAXED, __HIP_MEMORY_SCOPE_AGENT);
            ha[ks][1] = __hip_atomic_load(p + 1, __ATOMIC_RELAXED, __HIP_MEMORY_SCOPE_AGENT);
        }
        f32x4 acc[4];
        #pragma unroll
        for (int nf = 0; nf < 4; ++nf) acc[nf] = (f32x4){0.f, 0.f, 0.f, 0.f};
        #pragma unroll
        for (int ks = 0; ks < 16; ++ks) {
            union { ull q[2]; bf16x8 v; } au;
            au.q[0] = ha[ks][0]; au.q[1] = ha[ks][1];
            #pragma unroll
            for (int nf = 0; nf < 4; ++nf) {
                bf16x8 b = *(const bf16x8*)(Wl + (nf * 16 + l15) * 520 + ks * 32 + lhi * 8);
                acc[nf] = __builtin_amdgcn_mfma_f32_16x16x32_bf16(au.v, b, acc[nf], 0, 0, 0);
            }
        }
        #pragma unroll
        for (int q = 0; q < 4; ++q) {
            const int b = w * 16 + lhi * 4 + q;
            float gi = acc[0][q] + xg[0][q];
            float gf = acc[1][q] + xg[1][q];
            float gg = acc[2][q] + xg[2][q];
            float go = acc[3][q] + xg[3][q];
            float si = 1.f / (1.f + __expf(-gi));
            float sf = 1.f / (1.f + __expf(-gf));
            float tg = tanhf(gg);
            float so = 1.f / (1.f + __expf(-go));
            float cc = sf * cst[q] + si * tg;
            cst[q] = cc;
            uint16_t hv = f2bf(so * tanhf(cc));
            __hip_atomic_store(hs + (size_t)(t * 64 + b) * H_ + u0 + l15, hv,
                               __ATOMIC_RELAXED, __HIP_MEMORY_SCOPE_AGENT);
        }
        __syncthreads();                  // drains all waves' stores (vmcnt(0) before s_barrier)
        if (tid == 0) {
            __hip_atomic_fetch_add(bar, 1, __ATOMIC_RELAXED, __HIP_MEMORY_SCOPE_AGENT);
            const int target = 32 * (t + 1);
            while (__hip_atomic_load(bar, __ATOMIC_RELAXED, __HIP_MEMORY_SCOPE_AGENT) < target)
                __builtin_amdgcn_s_sleep(1);
        }
        __syncthreads();                  // next iteration's loads issue only after this
    }
}

// ---------------------------------------------------------------- K3: FC + lse (bf16 MFMA)
// tile 128 x 256, BK=64, 4 waves (wave -> 64 cols, 8 m-frags). 1D grid 3250,
// bijective XCD swizzle: each XCD sweeps a contiguous fc_W slice (~4MB = L2).
template<int CVT>
__global__ __launch_bounds__(256, 2) void k3_mfma(const uint16_t* __restrict__ hsb,
                                                  const void* __restrict__ fcw,
                                                  const float* __restrict__ fc_b,
                                                  const int* __restrict__ labels,
                                                  float* __restrict__ sumexp,
                                                  float* __restrict__ tgtlog) {
    __shared__ uint16_t Al[128 * 72];
    __shared__ uint16_t Bl[256 * 72];
    // swizzle: 3250 = 8*406+2 ; xcd<2 get 407 works
    const int flat = blockIdx.x;
    const int xcd  = flat & 7;
    const int slot = flat >> 3;
    const int work = (xcd < 2 ? xcd * 407 : 814 + (xcd - 2) * 406) + slot;
    const int m0   = (work % 26) * 128;
    const int v0   = (work / 26) * 256;
    const int tid  = threadIdx.x;
    const int w    = tid >> 6;
    const int lane = tid & 63;
    const int l15  = lane & 15;
    const int lhi  = lane >> 4;

    f32x4 acc[8][4];
    #pragma unroll
    for (int mi = 0; mi < 8; ++mi)
        #pragma unroll
        for (int nf = 0; nf < 4; ++nf) acc[mi][nf] = (f32x4){0.f, 0.f, 0.f, 0.f};

    for (int k0 = 0; k0 < H_; k0 += 64) {
        #pragma unroll
        for (int r = 0; r < 4; ++r) {       // A: 128 rows x 64
            int idx = r * 256 + tid, row = idx >> 3, seg = idx & 7;
            int grow = m0 + row; if (grow >= R_) grow = R_ - 1;
            *(uint4*)(Al + row * 72 + seg * 8) =
                *(const uint4*)(hsb + (size_t)grow * H_ + k0 + seg * 8);
        }
        #pragma unroll
        for (int r = 0; r < 8; ++r) {       // B: 256 rows x 64
            int idx = r * 256 + tid, row = idx >> 3, seg = idx & 7;
            if (CVT) {
                const float* s = (const float*)fcw + (size_t)(v0 + row) * H_ + k0 + seg * 8;
                float4 f0 = *(const float4*)s;
                float4 f1 = *(const float4*)(s + 4);
                union { uint16_t h[8]; uint4 u; } p;
                p.h[0]=f2bf(f0.x); p.h[1]=f2bf(f0.y); p.h[2]=f2bf(f0.z); p.h[3]=f2bf(f0.w);
                p.h[4]=f2bf(f1.x); p.h[5]=f2bf(f1.y); p.h[6]=f2bf(f1.z); p.h[7]=f2bf(f1.w);
                *(uint4*)(Bl + row * 72 + seg * 8) = p.u;
            } else {
                *(uint4*)(Bl + row * 72 + seg * 8) =
                    *(const uint4*)((const uint16_t*)fcw + (size_t)(v0 + row) * H_ + k0 + seg * 8);
            }
        }
        __syncthreads();
        #pragma unroll
        for (int ks = 0; ks < 2; ++ks) {
            bf16x8 a[8];
            #pragma unroll
            for (int mi = 0; mi < 8; ++mi)
                a[mi] = *(const bf16x8*)(Al + (mi * 16 + l15) * 72 + ks * 32 + lhi * 8);
            #pragma unroll
            for (int nf = 0; nf < 4; ++nf) {
                bf16x8 b = *(const bf16x8*)(Bl + (w * 64 + nf * 16 + l15) * 72 + ks * 32 + lhi * 8);
                #pragma unroll
                for (int mi = 0; mi < 8; ++mi)
                    acc[mi][nf] = __builtin_amdgcn_mfma_f32_16x16x32_bf16(a[mi], b, acc[mi][nf], 0, 0, 0);
            }
        }
        __syncthreads();
    }
    float bias[4];
    #pragma unroll
    for (int nf = 0; nf < 4; ++nf) bias[nf] = fc_b[v0 + w * 64 + nf * 16 + l15];
    #pragma unroll
    for (int mi = 0; mi < 8; ++mi) {
        #pragma unroll
        for (int q = 0; q < 4; ++q) {
            const int r = m0 + mi * 16 + lhi * 4 + q;
            if (r >= R_) continue;
            const int t = r >> 6, b = r & 63;
            const int tgt = (t < 50) ? labels[b * 50 + t] : 2;
            float lsum = 0.f;
            #pragma unroll
            for (int nf = 0; nf < 4; ++nf) {
                const int v = v0 + w * 64 + nf * 16 + l15;
                float lg = acc[mi][nf][q] + bias[nf];
                lsum += __expf(lg);
                if (v == tgt) tgtlog[r] = lg;
            }
            lsum += __shfl_xor(lsum, 1, 16);
            lsum += __shfl_xor(lsum, 2, 16);
            lsum += __shfl_xor(lsum, 4, 16);
            lsum += __shfl_xor(lsum, 8, 16);
            if (l15 == 0) atomicAdd(&sumexp[r], lsum);
        }
    }
}

// ---------------------------------------------------------------- K4: loss
__global__ __launch_bounds__(256) void k4_loss(const float* __restrict__ sumexp,
                                               const float* __restrict__ tgtlog,
                                               float* __restrict__ out) {
    __shared__ float red[256];
    float s = 0.f;
    for (int r = threadIdx.x; r < R_; r += 256) s += logf(sumexp[r]) - tgtlog[r];
    red[threadIdx.x] = s;
    __syncthreads();
    for (int st = 128; st > 0; st >>= 1) {
        if (threadIdx.x < st) red[threadIdx.x] += red[threadIdx.x + st];
        __syncthreads();
    }
    if (threadIdx.x == 0) out[0] = red[0] / 64.0f;
}

// ----------------------------------------------------------------
extern "C" void kernel_launch(void* const* d_in, const int* in_sizes, int n_in,
                              void* d_out, int out_size, void* d_ws, size_t ws_size,
                              hipStream_t stream) {
    const float* x      = (const float*)d_in[0];
    const int*   labels = (const int*)d_in[1];
    const float* emb    = (const float*)d_in[2];
    const float* W_ih   = (const float*)d_in[3];
    const float* W_hh   = (const float*)d_in[4];
    const float* b_ih   = (const float*)d_in[5];
    const float* b_hh   = (const float*)d_in[6];
    const float* fc_W   = (const float*)d_in[7];
    const float* fc_b   = (const float*)d_in[8];
    float* out = (float*)d_out;

    char* p = (char*)d_ws;
    float*    Xg     = (float*)p;     p += (size_t)R_ * G4_ * 4;   // 26.7 MB
    uint16_t* hsb    = (uint16_t*)p;  p += (size_t)R_ * H_ * 2;    // 3.3 MB
    uint16_t* hx     = (uint16_t*)p;  p += (size_t)B_ * H_ * 2;
    float*    sumexp = (float*)p;     p += (size_t)R_ * 4;
    float*    tgtl   = (float*)p;     p += (size_t)R_ * 4;
    int*      bar    = (int*)p;       p += 64;
    uint16_t* fcwb   = (uint16_t*)p;  p += (size_t)V_ * H_ * 2;    // 32.8 MB
    uint16_t* wihb   = (uint16_t*)p;  p += (size_t)G4_ * H_ * 2;   // 2.1 MB
    const bool pre = ((size_t)(p - (char*)d_ws) <= ws_size);

    k0_init<<<128, 256, 0, stream>>>(x, hx, sumexp, bar);
    if (pre) {
        kcvt<<<8000, 256, 0, stream>>>(fc_W, fcwb, (V_ * H_) / 8);
        kcvt<<<512, 256, 0, stream>>>(W_ih, wihb, (G4_ * H_) / 8);
        k1_mfma<0><<<dim3(8, 51), 256, 0, stream>>>(labels, emb, wihb, b_ih, b_hh, Xg);
    } else {
        k1_mfma<1><<<dim3(8, 51), 256, 0, stream>>>(labels, emb, W_ih, b_ih, b_hh, Xg);
    }
    k2p<<<32, 256, 64 * 520 * 2, stream>>>(hx, x, Xg, W_hh, hsb, bar);
    if (pre) k3_mfma<0><<<3250, 256, 0, stream>>>(hsb, fcwb, fc_b, labels, sumexp, tgtl);
    else     k3_mfma<1><<<3250, 256, 0, stream>>>(hsb, fc_W, fc_b, labels, sumexp, tgtl);
    k4_loss<<<1, 256, 0, stream>>>(sumexp, tgtl, out);
}